// Round 10
// baseline (1215.041 us; speedup 1.0000x reference)
//
#include <hip/hip_runtime.h>
#include <math.h>

constexpr int Bc = 16;
constexpr int Nc = 8192;
constexpr int Sc = 512;
constexpr int Kc = 32;
constexpr int Pc = Bc * Sc * Kc; // 262144

constexpr int NBALL_BLK = 240;             // ball blocks (+16 FPS = 256 total)
constexpr int NBALL_WAVES = NBALL_BLK * 4; // 960 (60 waves per batch, stride 60)

typedef float v2f __attribute__((ext_vector_type(2)));

#if defined(__has_builtin)
#if __has_builtin(__builtin_elementwise_fma)
#define PKFMA(a, b, c) __builtin_elementwise_fma(a, b, c)
#endif
#endif
#ifndef PKFMA
__device__ __forceinline__ v2f pkfma_(v2f a, v2f b, v2f c) {
  v2f r; r.x = fmaf(a.x, b.x, c.x); r.y = fmaf(a.y, b.y, c.y); return r;
}
#define PKFMA(a, b, c) pkfma_(a, b, c)
#endif

// DPP-assisted wave64 max stage (ctrl is a compile-time constant)
template <int CTRL>
__device__ __forceinline__ float dpp_max_stage(float x) {
  int p = __builtin_amdgcn_update_dpp(0, __float_as_int(x), CTRL, 0xf, 0xf, true);
  return fmaxf(x, __int_as_float(p));
}

// ---------------------------------------------------------------------------
// Fused FPS + ball query producer/consumer kernel — EXACT round-0 config
// (measured 488-495us, stable across r1/r2/r5/r7/r8/r9). Do not touch.
// ---------------------------------------------------------------------------
__global__ __launch_bounds__(256, 1)
void fps_ball_fused(const float* __restrict__ data,
                    const float* __restrict__ feat,
                    const float* __restrict__ w0,
                    const float* __restrict__ b0,
                    int* __restrict__ idx_pub,
                    float* __restrict__ cent_out,
                    float* __restrict__ x0,
                    float* __restrict__ part0) {
  __shared__ float lx[Nc], ly[Nc], lz[Nc];          // 96 KB point mirror (FPS)
  __shared__ unsigned long long red_k[2][4];
  __shared__ int idx_hist[Sc];
  __shared__ int nbr[4][Kc];                        // per-wave (ball)
  __shared__ float x0s[4][6][Kc];                   // per-wave (ball)

  const int t = threadIdx.x;
  const int lane = t & 63, w = t >> 6;

  if (blockIdx.x < Bc) {
    // ------------------------------ FPS ---------------------------------
    const int b = blockIdx.x;
    const float* db = data + (size_t)b * Nc * 3;

    float px[32], py[32], pz[32], dist[32];
#pragma unroll
    for (int j = 0; j < 32; ++j) {
      int p = t + 256 * j;
      px[j] = db[p * 3 + 0];
      py[j] = db[p * 3 + 1];
      pz[j] = db[p * 3 + 2];
      dist[j] = 1e10f;
      lx[p] = px[j]; ly[p] = py[j]; lz[p] = pz[j];
    }
    __syncthreads();

    int far = 0;
    for (int it = 0; it < Sc; ++it) {
      const int sfar = __builtin_amdgcn_readfirstlane(far);
      if (t == 0) {
        idx_hist[it] = sfar;
        atomicExch(&idx_pub[(b << 9) + it], sfar);  // publish, fire-and-forget
      }
      const float cx = lx[sfar];
      const float cy = ly[sfar];
      const float cz = lz[sfar];

      float best = -1.0f; int bj = 0;
#pragma unroll
      for (int j = 0; j < 32; ++j) {
        float dx = __fsub_rn(px[j], cx);
        float dy = __fsub_rn(py[j], cy);
        float dz = __fsub_rn(pz[j], cz);
        float d = __fadd_rn(__fadd_rn(__fmul_rn(dx, dx), __fmul_rn(dy, dy)),
                            __fmul_rn(dz, dz));
        float nd = fminf(dist[j], d);
        dist[j] = nd;
        if (nd > best) { best = nd; bj = j; }  // strict >: first index in lane
      }
      const int bidx = t + 256 * bj;

      float wmax = best;
      wmax = dpp_max_stage<0xB1>(wmax);   // quad_perm [1,0,3,2]
      wmax = dpp_max_stage<0x4E>(wmax);   // quad_perm [2,3,0,1]
      wmax = dpp_max_stage<0x141>(wmax);  // row_half_mirror
      wmax = dpp_max_stage<0x140>(wmax);  // row_mirror
      wmax = fmaxf(wmax, __shfl_xor(wmax, 16));
      wmax = fmaxf(wmax, __shfl_xor(wmax, 32));

      unsigned long long m = __ballot(best == wmax);
      int idx;
      if (__popcll(m) == 1) {
        idx = __shfl(bidx, (int)__ffsll((long long)m) - 1);
      } else {
        int cand = (best == wmax) ? bidx : 0x7fffffff;
#pragma unroll
        for (int off = 32; off; off >>= 1) cand = min(cand, __shfl_xor(cand, off));
        idx = cand;
      }

      unsigned long long key =
          ((unsigned long long)__float_as_uint(wmax) << 32) |
          (unsigned long long)(0xFFFFFFFFu - (unsigned)idx);
      const int par = it & 1;
      if (lane == 0) red_k[par][w] = key;
      __syncthreads();

      unsigned long long k0 = red_k[par][0];
      unsigned long long k1 = red_k[par][1];
      unsigned long long k2 = red_k[par][2];
      unsigned long long k3 = red_k[par][3];
      unsigned long long ka = (k0 > k1) ? k0 : k1;
      unsigned long long kb = (k2 > k3) ? k2 : k3;
      unsigned long long kk = (ka > kb) ? ka : kb;
      far = (int)(0xFFFFFFFFu - (unsigned)(kk & 0xFFFFFFFFull));
    }

    __syncthreads();
    for (int s = t; s < Sc; s += 256) {
      int id = idx_hist[s];
      size_t o = ((size_t)b * Sc + s) * 3;
      cent_out[o + 0] = lx[id];
      cent_out[o + 1] = ly[id];
      cent_out[o + 2] = lz[id];
    }
  } else {
    // --------------------------- ball query ------------------------------
    const int wid = (blockIdx.x - Bc) * 4 + w;   // 0..959
    const int bb = wid & 15;                     // batch (batch-isolated wave)
    const int u  = wid >> 4;                     // 0..59
    const float* db = data + (size_t)bb * Nc * 3;
    const float* fb = feat + (size_t)bb * Nc * 3;

    float W[6];
#pragma unroll
    for (int c = 0; c < 6; ++c) W[c] = w0[lane * 6 + c];
    const float bias = b0[lane];
    float sum = 0.f, sq = 0.f;

    for (int s = u; s < Sc; s += 60) {
      const int q = bb * Sc + s;

      // prefetch chunk 0 while (possibly) waiting for the centroid index
      float px = db[lane * 3 + 0];
      float py = db[lane * 3 + 1];
      float pz = db[lane * 3 + 2];

      int ci;
      for (;;) {
        int t0 = -1;
        if (lane == 0) t0 = atomicAdd(&idx_pub[q], 0);  // coherent RMW read
        ci = __shfl(t0, 0);
        if (ci >= 0) break;
        __builtin_amdgcn_s_sleep(32);   // ~2k cycles between polls
      }

      const float qx = db[ci * 3 + 0];
      const float qy = db[ci * 3 + 1];
      const float qz = db[ci * 3 + 2];
      const float q2 = __fadd_rn(__fadd_rn(__fmul_rn(qx, qx), __fmul_rn(qy, qy)),
                                 __fmul_rn(qz, qz));

      int have = 0;
      for (int base = 0; base < Nc; base += 64) {
        // software pipeline: issue next chunk's loads before the ballot/break
        const int inext = (base + 64 + lane) & (Nc - 1);
        float nx = db[inext * 3 + 0];
        float ny = db[inext * 3 + 1];
        float nz = db[inext * 3 + 2];

        float p2 = __fadd_rn(__fadd_rn(__fmul_rn(px, px), __fmul_rn(py, py)),
                             __fmul_rn(pz, pz));
        float dt = fmaf(qz, pz, fmaf(qy, py, __fmul_rn(qx, px)));
        float d = __fadd_rn(__fadd_rn(__fmul_rn(-2.0f, dt), q2), p2);
        bool ok = d <= 0.16f;
        unsigned long long mask = __ballot(ok);
        if (mask) {
          int pos = have + __popcll(mask & ((1ull << lane) - 1ull));
          if (ok && pos < Kc) nbr[w][pos] = base + lane;
          have += __popcll(mask);
          if (have >= Kc) break;
        }
        px = nx; py = ny; pz = nz;
      }
      if (have > Kc) have = Kc;

      // gather + x0 write (wave-local; compiler orders ds_write -> ds_read)
      if (lane < Kc) {
        int j = nbr[w][lane < have ? lane : 0];
        float sx = __fsub_rn(db[j * 3 + 0], qx);
        float sy = __fsub_rn(db[j * 3 + 1], qy);
        float sz = __fsub_rn(db[j * 3 + 2], qz);
        float fx = fb[j * 3 + 0], fy = fb[j * 3 + 1], fz = fb[j * 3 + 2];
        size_t pidx = (size_t)q * Kc + lane;
        x0[(size_t)0 * Pc + pidx] = sx;
        x0[(size_t)1 * Pc + pidx] = sy;
        x0[(size_t)2 * Pc + pidx] = sz;
        x0[(size_t)3 * Pc + pidx] = fx;
        x0[(size_t)4 * Pc + pidx] = fy;
        x0[(size_t)5 * Pc + pidx] = fz;
        x0s[w][0][lane] = sx; x0s[w][1][lane] = sy; x0s[w][2][lane] = sz;
        x0s[w][3][lane] = fx; x0s[w][4][lane] = fy; x0s[w][5][lane] = fz;
      }

      // y0 = conv0(x0)+b0 partial stats: lane = channel, broadcast LDS reads
#pragma unroll 4
      for (int k = 0; k < Kc; ++k) {
        float y = bias;
#pragma unroll
        for (int c = 0; c < 6; ++c) y = fmaf(x0s[w][c][k], W[c], y);
        sum += y;
        sq = fmaf(y, y, sq);
      }
    }
    part0[(size_t)wid * 128 + lane] = sum;
    part0[(size_t)wid * 128 + 64 + lane] = sq;
  }
}

// One block per channel; 256-thread fixed-order tree (deterministic, double).
__global__ __launch_bounds__(256)
void reduce_k(const float* __restrict__ part, int nblk, int nch,
              const float* __restrict__ g, const float* __restrict__ be,
              float* __restrict__ AB) {
  const int o = blockIdx.x;
  const int t = threadIdx.x;
  double sum = 0.0, sq = 0.0;
  for (int i = t; i < nblk; i += 256) {
    sum += (double)part[(size_t)i * (2 * nch) + o];
    sq  += (double)part[(size_t)i * (2 * nch) + nch + o];
  }
  __shared__ double ls[256], lq[256];
  ls[t] = sum; lq[t] = sq;
  __syncthreads();
  for (int s = 128; s > 0; s >>= 1) {
    if (t < s) { ls[t] += ls[t + s]; lq[t] += lq[t + s]; }
    __syncthreads();
  }
  if (t == 0) {
    double m = ls[0] / (double)Pc;
    double v = lq[0] / (double)Pc - m * m;
    double A = (double)g[o] / sqrt(v + 1e-5);
    AB[o] = (float)A;
    AB[nch + o] = (float)((double)be[o] - m * A);
  }
}

// reduce layer-2 stats fused with the final affine+relu epilogue.
__global__ __launch_bounds__(256)
void reduce2_final_k(const float* __restrict__ part, int nblk,
                     const float* __restrict__ g, const float* __restrict__ be,
                     const float* __restrict__ maxy2,
                     float* __restrict__ out) {
  const int o = blockIdx.x;          // 0..127
  const int t = threadIdx.x;
  double sum = 0.0, sq = 0.0;
  for (int i = t; i < nblk; i += 256) {
    sum += (double)part[(size_t)i * 256 + o];
    sq  += (double)part[(size_t)i * 256 + 128 + o];
  }
  __shared__ double ls[256], lq[256];
  ls[t] = sum; lq[t] = sq;
  __syncthreads();
  for (int s = 128; s > 0; s >>= 1) {
    if (t < s) { ls[t] += ls[t + s]; lq[t] += lq[t + s]; }
    __syncthreads();
  }
  __shared__ float sA, sB;
  if (t == 0) {
    double m = ls[0] / (double)Pc;
    double v = lq[0] / (double)Pc - m * m;
    double A = (double)g[o] / sqrt(v + 1e-5);
    sA = (float)A;
    sB = (float)((double)be[o] - m * A);
  }
  __syncthreads();
  const float A = sA, B = sB;
  for (int grp = t; grp < Bc * Sc; grp += 256) {
    float v = maxy2[(size_t)grp * 128 + o];
    out[(size_t)grp * 128 + o] = fmaxf(fmaf(v, A, B), 0.f);
  }
}

// pass_b MINIMAL (r9 form, unchanged): conv0 -> BN0+relu -> conv1 -> y1.
__global__ __launch_bounds__(256, 1)
void pass_b(const float* __restrict__ x0, const float* __restrict__ w0,
            const float* __restrict__ b0, const float* __restrict__ AB0,
            const float* __restrict__ w1, const float* __restrict__ b1,
            float* __restrict__ y1) {
  const int p = blockIdx.x * 256 + threadIdx.x;

  float xin[6];
#pragma unroll
  for (int c = 0; c < 6; ++c) xin[c] = x0[(size_t)c * Pc + p];

  v2f x1p[32];
#pragma unroll
  for (int j = 0; j < 32; ++j) {
    float y0v = b0[2 * j];
#pragma unroll
    for (int c = 0; c < 6; ++c) y0v = fmaf(xin[c], w0[(2 * j) * 6 + c], y0v);
    x1p[j].x = fmaxf(fmaf(y0v, AB0[2 * j], AB0[64 + 2 * j]), 0.f);
    float y1v = b0[2 * j + 1];
#pragma unroll
    for (int c = 0; c < 6; ++c) y1v = fmaf(xin[c], w0[(2 * j + 1) * 6 + c], y1v);
    x1p[j].y = fmaxf(fmaf(y1v, AB0[2 * j + 1], AB0[64 + 2 * j + 1]), 0.f);
  }

  const v2f* __restrict__ w1v = (const v2f*)w1;

  for (int o = 0; o < 64; ++o) {
    v2f a01; a01.x = b1[o]; a01.y = 0.f;
    v2f a23; a23.x = 0.f;   a23.y = 0.f;
#pragma unroll
    for (int c2 = 0; c2 < 32; c2 += 2) {
      a01 = PKFMA(x1p[c2 + 0], w1v[o * 32 + c2 + 0], a01);
      a23 = PKFMA(x1p[c2 + 1], w1v[o * 32 + c2 + 1], a23);
    }
    y1[(size_t)o * Pc + p] = (a01.x + a01.y) + (a23.x + a23.y);
  }
}

// stats1_k: per-channel sum/sumsq partials from the y1 planes (r9 form).
__global__ __launch_bounds__(256)
void stats1_k(const float* __restrict__ y1, float* __restrict__ pair1) {
  const int b = blockIdx.x;
  const int o = b >> 4, seg = b & 15;
  const int t = threadIdx.x;
  const float* plane = y1 + (size_t)o * Pc + (size_t)seg * 16384;
  float sum = 0.f, sq = 0.f;
  for (int i = t; i < 16384; i += 256) {
    float v = plane[i];
    sum += v;
    sq = fmaf(v, v, sq);
  }
  __shared__ float ls[256], lq[256];
  ls[t] = sum; lq[t] = sq;
  __syncthreads();
  for (int s = 128; s > 0; s >>= 1) {
    if (t < s) { ls[t] += ls[t + s]; lq[t] += lq[t + s]; }
    __syncthreads();
  }
  if (t == 0) {
    pair1[(size_t)b * 2 + 0] = ls[0];
    pair1[(size_t)b * 2 + 1] = lq[0];
  }
}

// Tiny deterministic double reduce over the 16 segment pairs per channel.
__global__ __launch_bounds__(64)
void reduceAB_pairs_k(const float* __restrict__ pair, int nseg,
                      const float* __restrict__ g, const float* __restrict__ be,
                      float* __restrict__ AB, int nch) {
  const int o = blockIdx.x;
  if (threadIdx.x == 0) {
    double sum = 0.0, sq = 0.0;
    for (int s = 0; s < nseg; ++s) {
      sum += (double)pair[(size_t)(o * nseg + s) * 2 + 0];
      sq  += (double)pair[(size_t)(o * nseg + s) * 2 + 1];
    }
    double m = sum / (double)Pc;
    double v = sq / (double)Pc - m * m;
    double A = (double)g[o] / sqrt(v + 1e-5);
    AB[o] = (float)A;
    AB[nch + o] = (float)((double)be[o] - m * A);
  }
}

// pass_c: unchanged (r8/r9 form). PURE FUNCTION of (y1, AB1, w2, b2) ->
// (maxy2, part2): relaunching it is idempotent and bit-identical, which
// round 10 exploits as a measurement device (see kernel_launch).
__global__ __launch_bounds__(256, 1)
void pass_c(const float* __restrict__ y1, const float* __restrict__ AB1,
            const float* __restrict__ w2, const float* __restrict__ b2,
            float* __restrict__ maxy2, float* __restrict__ part2) {
  const int p = blockIdx.x * 256 + threadIdx.x;
  const int lane = threadIdx.x & 63, w = threadIdx.x >> 6;
  const int grp = p >> 5;

  v2f x2p[32];
#pragma unroll
  for (int c = 0; c < 64; c += 2) {
    float v0 = y1[(size_t)c * Pc + p];
    float v1 = y1[(size_t)(c + 1) * Pc + p];
    x2p[c >> 1].x = fmaxf(fmaf(v0, AB1[c], AB1[64 + c]), 0.f);
    x2p[c >> 1].y = fmaxf(fmaf(v1, AB1[c + 1], AB1[64 + c + 1]), 0.f);
  }

  const v2f* __restrict__ w2v = (const v2f*)w2;

  __shared__ float ssum[4][128][9], ssq[4][128][9];  // padded: stride 9

  for (int o = 0; o < 128; ++o) {
    v2f a01; a01.x = b2[o]; a01.y = 0.f;
    v2f a23; a23.x = 0.f;   a23.y = 0.f;
#pragma unroll
    for (int c2 = 0; c2 < 32; c2 += 2) {
      a01 = PKFMA(x2p[c2 + 0], w2v[o * 32 + c2 + 0], a01);
      a23 = PKFMA(x2p[c2 + 1], w2v[o * 32 + c2 + 1], a23);
    }
    float acc = (a01.x + a01.y) + (a23.x + a23.y);

    float mx = acc;
#pragma unroll
    for (int off = 16; off > 0; off >>= 1) mx = fmaxf(mx, __shfl_xor(mx, off));
    if ((lane & 31) == 0) maxy2[(size_t)grp * 128 + o] = mx;

    float sv = acc + __shfl_xor(acc, 1);
    sv += __shfl_xor(sv, 2);
    sv += __shfl_xor(sv, 4);
    float q = acc * acc;
    float qv = q + __shfl_xor(q, 1);
    qv += __shfl_xor(qv, 2);
    qv += __shfl_xor(qv, 4);
    if ((lane & 7) == 0) {
      ssum[w][o][lane >> 3] = sv;
      ssq[w][o][lane >> 3] = qv;
    }
  }
  __syncthreads();
  {
    const int o = threadIdx.x & 127;
    const bool isq = threadIdx.x >= 128;
    float s = 0.f;
#pragma unroll
    for (int ww = 0; ww < 4; ++ww)
      for (int k = 0; k < 8; ++k)
        s += isq ? ssq[ww][o][k] : ssum[ww][o][k];
    part2[blockIdx.x * 256 + threadIdx.x] = s;
  }
}

extern "C" void kernel_launch(void* const* d_in, const int* in_sizes, int n_in,
                              void* d_out, int out_size, void* d_ws, size_t ws_size,
                              hipStream_t stream) {
  const float* data = (const float*)d_in[0];
  const float* feat = (const float*)d_in[1];
  const float* w0 = (const float*)d_in[2];
  const float* b0 = (const float*)d_in[3];
  const float* g0 = (const float*)d_in[4];
  const float* be0 = (const float*)d_in[5];
  const float* w1 = (const float*)d_in[6];
  const float* b1 = (const float*)d_in[7];
  const float* g1 = (const float*)d_in[8];
  const float* be1 = (const float*)d_in[9];
  const float* w2 = (const float*)d_in[10];
  const float* b2 = (const float*)d_in[11];
  const float* g2 = (const float*)d_in[12];
  const float* be2 = (const float*)d_in[13];
  float* out = (float*)d_out;

  float* ws = (float*)d_ws;
  int* idx_pub = (int*)ws; ws += (size_t)Bc * Sc;      // 8192 ints
  float* x0 = ws;      ws += (size_t)6 * Pc;
  float* y1 = ws;      ws += (size_t)64 * Pc;          // [ch][point] planes
  float* maxy2 = ws;   ws += (size_t)Bc * Sc * 128;
  float* part0 = ws;   ws += (size_t)NBALL_WAVES * 128;
  float* pair1 = ws;   ws += 1024 * 2;
  float* part2 = ws;   ws += 1024 * 256;
  float* AB0 = ws;     ws += 128;
  float* AB1 = ws;     ws += 128;

  // re-poison the publication slots every graph replay
  hipMemsetAsync(idx_pub, 0xFF, (size_t)Bc * Sc * sizeof(int), stream);

  fps_ball_fused<<<Bc + NBALL_BLK, 256, 0, stream>>>(data, feat, w0, b0,
                                                     idx_pub, out, x0, part0);
  reduce_k<<<64, 256, 0, stream>>>(part0, NBALL_WAVES, 64, g0, be0, AB0);
  pass_b<<<Pc / 256, 256, 0, stream>>>(x0, w0, b0, AB0, w1, b1, y1);
  stats1_k<<<1024, 256, 0, stream>>>(y1, pair1);
  reduceAB_pairs_k<<<64, 64, 0, stream>>>(pair1, 16, g1, be1, AB1, 64);

  // -------------------------------------------------------------------------
  // ROUND-10 MEASUREMENT: launch pass_c 4x (idempotent: pure function of its
  // inputs, rewrites identical values). The bench total becomes an in-band
  // probe of pass_c's true duration: tc ~= (total - 787us)/3 - gap.
  // This splits the stubborn ~295us downstream phantom into {pass_c} vs
  // {pass_b + stats + reduces + gaps} with zero correctness risk.
  // Pre-committed fork: total ~1.4ms -> pass_c ~200us (attack its core);
  // total ~950 -> pass_b's y1 store path; total ~850 -> inter-kernel overhead.
  // -------------------------------------------------------------------------
  for (int rep = 0; rep < 4; ++rep)
    pass_c<<<Pc / 256, 256, 0, stream>>>(y1, AB1, w2, b2, maxy2, part2);

  reduce2_final_k<<<128, 256, 0, stream>>>(part2, 1024, g2, be2, maxy2,
                                           out + (size_t)Bc * Sc * 3);
}

// Round 11
// 765.872 us; speedup vs baseline: 1.5865x; 1.5865x over previous
//
#include <hip/hip_runtime.h>
#include <math.h>

constexpr int Bc = 16;
constexpr int Nc = 8192;
constexpr int Sc = 512;
constexpr int Kc = 32;
constexpr int Pc = Bc * Sc * Kc; // 262144

constexpr int NBALL_BLK = 240;             // ball blocks (+16 FPS = 256 total)
constexpr int NBALL_WAVES = NBALL_BLK * 4; // 960 (60 waves per batch, stride 60)

typedef float v2f __attribute__((ext_vector_type(2)));

#if defined(__has_builtin)
#if __has_builtin(__builtin_elementwise_fma)
#define PKFMA(a, b, c) __builtin_elementwise_fma(a, b, c)
#endif
#endif
#ifndef PKFMA
__device__ __forceinline__ v2f pkfma_(v2f a, v2f b, v2f c) {
  v2f r; r.x = fmaf(a.x, b.x, c.x); r.y = fmaf(a.y, b.y, c.y); return r;
}
#define PKFMA(a, b, c) pkfma_(a, b, c)
#endif

// DPP-assisted wave64 max stage (ctrl is a compile-time constant)
template <int CTRL>
__device__ __forceinline__ float dpp_max_stage(float x) {
  int p = __builtin_amdgcn_update_dpp(0, __float_as_int(x), CTRL, 0xf, 0xf, true);
  return fmaxf(x, __int_as_float(p));
}

// ---------------------------------------------------------------------------
// Fused FPS + ball query producer/consumer kernel — EXACT round-0 config
// (measured 486-495us, stable across r1/r2/r5/r7-r10). Do not touch.
// ---------------------------------------------------------------------------
__global__ __launch_bounds__(256, 1)
void fps_ball_fused(const float* __restrict__ data,
                    const float* __restrict__ feat,
                    const float* __restrict__ w0,
                    const float* __restrict__ b0,
                    int* __restrict__ idx_pub,
                    float* __restrict__ cent_out,
                    float* __restrict__ x0,
                    float* __restrict__ part0) {
  __shared__ float lx[Nc], ly[Nc], lz[Nc];          // 96 KB point mirror (FPS)
  __shared__ unsigned long long red_k[2][4];
  __shared__ int idx_hist[Sc];
  __shared__ int nbr[4][Kc];                        // per-wave (ball)
  __shared__ float x0s[4][6][Kc];                   // per-wave (ball)

  const int t = threadIdx.x;
  const int lane = t & 63, w = t >> 6;

  if (blockIdx.x < Bc) {
    // ------------------------------ FPS ---------------------------------
    const int b = blockIdx.x;
    const float* db = data + (size_t)b * Nc * 3;

    float px[32], py[32], pz[32], dist[32];
#pragma unroll
    for (int j = 0; j < 32; ++j) {
      int p = t + 256 * j;
      px[j] = db[p * 3 + 0];
      py[j] = db[p * 3 + 1];
      pz[j] = db[p * 3 + 2];
      dist[j] = 1e10f;
      lx[p] = px[j]; ly[p] = py[j]; lz[p] = pz[j];
    }
    __syncthreads();

    int far = 0;
    for (int it = 0; it < Sc; ++it) {
      const int sfar = __builtin_amdgcn_readfirstlane(far);
      if (t == 0) {
        idx_hist[it] = sfar;
        atomicExch(&idx_pub[(b << 9) + it], sfar);  // publish, fire-and-forget
      }
      const float cx = lx[sfar];
      const float cy = ly[sfar];
      const float cz = lz[sfar];

      float best = -1.0f; int bj = 0;
#pragma unroll
      for (int j = 0; j < 32; ++j) {
        float dx = __fsub_rn(px[j], cx);
        float dy = __fsub_rn(py[j], cy);
        float dz = __fsub_rn(pz[j], cz);
        float d = __fadd_rn(__fadd_rn(__fmul_rn(dx, dx), __fmul_rn(dy, dy)),
                            __fmul_rn(dz, dz));
        float nd = fminf(dist[j], d);
        dist[j] = nd;
        if (nd > best) { best = nd; bj = j; }  // strict >: first index in lane
      }
      const int bidx = t + 256 * bj;

      float wmax = best;
      wmax = dpp_max_stage<0xB1>(wmax);   // quad_perm [1,0,3,2]
      wmax = dpp_max_stage<0x4E>(wmax);   // quad_perm [2,3,0,1]
      wmax = dpp_max_stage<0x141>(wmax);  // row_half_mirror
      wmax = dpp_max_stage<0x140>(wmax);  // row_mirror
      wmax = fmaxf(wmax, __shfl_xor(wmax, 16));
      wmax = fmaxf(wmax, __shfl_xor(wmax, 32));

      unsigned long long m = __ballot(best == wmax);
      int idx;
      if (__popcll(m) == 1) {
        idx = __shfl(bidx, (int)__ffsll((long long)m) - 1);
      } else {
        int cand = (best == wmax) ? bidx : 0x7fffffff;
#pragma unroll
        for (int off = 32; off; off >>= 1) cand = min(cand, __shfl_xor(cand, off));
        idx = cand;
      }

      unsigned long long key =
          ((unsigned long long)__float_as_uint(wmax) << 32) |
          (unsigned long long)(0xFFFFFFFFu - (unsigned)idx);
      const int par = it & 1;
      if (lane == 0) red_k[par][w] = key;
      __syncthreads();

      unsigned long long k0 = red_k[par][0];
      unsigned long long k1 = red_k[par][1];
      unsigned long long k2 = red_k[par][2];
      unsigned long long k3 = red_k[par][3];
      unsigned long long ka = (k0 > k1) ? k0 : k1;
      unsigned long long kb = (k2 > k3) ? k2 : k3;
      unsigned long long kk = (ka > kb) ? ka : kb;
      far = (int)(0xFFFFFFFFu - (unsigned)(kk & 0xFFFFFFFFull));
    }

    __syncthreads();
    for (int s = t; s < Sc; s += 256) {
      int id = idx_hist[s];
      size_t o = ((size_t)b * Sc + s) * 3;
      cent_out[o + 0] = lx[id];
      cent_out[o + 1] = ly[id];
      cent_out[o + 2] = lz[id];
    }
  } else {
    // --------------------------- ball query ------------------------------
    const int wid = (blockIdx.x - Bc) * 4 + w;   // 0..959
    const int bb = wid & 15;                     // batch (batch-isolated wave)
    const int u  = wid >> 4;                     // 0..59
    const float* db = data + (size_t)bb * Nc * 3;
    const float* fb = feat + (size_t)bb * Nc * 3;

    float W[6];
#pragma unroll
    for (int c = 0; c < 6; ++c) W[c] = w0[lane * 6 + c];
    const float bias = b0[lane];
    float sum = 0.f, sq = 0.f;

    for (int s = u; s < Sc; s += 60) {
      const int q = bb * Sc + s;

      // prefetch chunk 0 while (possibly) waiting for the centroid index
      float px = db[lane * 3 + 0];
      float py = db[lane * 3 + 1];
      float pz = db[lane * 3 + 2];

      int ci;
      for (;;) {
        int t0 = -1;
        if (lane == 0) t0 = atomicAdd(&idx_pub[q], 0);  // coherent RMW read
        ci = __shfl(t0, 0);
        if (ci >= 0) break;
        __builtin_amdgcn_s_sleep(32);   // ~2k cycles between polls
      }

      const float qx = db[ci * 3 + 0];
      const float qy = db[ci * 3 + 1];
      const float qz = db[ci * 3 + 2];
      const float q2 = __fadd_rn(__fadd_rn(__fmul_rn(qx, qx), __fmul_rn(qy, qy)),
                                 __fmul_rn(qz, qz));

      int have = 0;
      for (int base = 0; base < Nc; base += 64) {
        // software pipeline: issue next chunk's loads before the ballot/break
        const int inext = (base + 64 + lane) & (Nc - 1);
        float nx = db[inext * 3 + 0];
        float ny = db[inext * 3 + 1];
        float nz = db[inext * 3 + 2];

        float p2 = __fadd_rn(__fadd_rn(__fmul_rn(px, px), __fmul_rn(py, py)),
                             __fmul_rn(pz, pz));
        float dt = fmaf(qz, pz, fmaf(qy, py, __fmul_rn(qx, px)));
        float d = __fadd_rn(__fadd_rn(__fmul_rn(-2.0f, dt), q2), p2);
        bool ok = d <= 0.16f;
        unsigned long long mask = __ballot(ok);
        if (mask) {
          int pos = have + __popcll(mask & ((1ull << lane) - 1ull));
          if (ok && pos < Kc) nbr[w][pos] = base + lane;
          have += __popcll(mask);
          if (have >= Kc) break;
        }
        px = nx; py = ny; pz = nz;
      }
      if (have > Kc) have = Kc;

      // gather + x0 write (wave-local; compiler orders ds_write -> ds_read)
      if (lane < Kc) {
        int j = nbr[w][lane < have ? lane : 0];
        float sx = __fsub_rn(db[j * 3 + 0], qx);
        float sy = __fsub_rn(db[j * 3 + 1], qy);
        float sz = __fsub_rn(db[j * 3 + 2], qz);
        float fx = fb[j * 3 + 0], fy = fb[j * 3 + 1], fz = fb[j * 3 + 2];
        size_t pidx = (size_t)q * Kc + lane;
        x0[(size_t)0 * Pc + pidx] = sx;
        x0[(size_t)1 * Pc + pidx] = sy;
        x0[(size_t)2 * Pc + pidx] = sz;
        x0[(size_t)3 * Pc + pidx] = fx;
        x0[(size_t)4 * Pc + pidx] = fy;
        x0[(size_t)5 * Pc + pidx] = fz;
        x0s[w][0][lane] = sx; x0s[w][1][lane] = sy; x0s[w][2][lane] = sz;
        x0s[w][3][lane] = fx; x0s[w][4][lane] = fy; x0s[w][5][lane] = fz;
      }

      // y0 = conv0(x0)+b0 partial stats: lane = channel, broadcast LDS reads
#pragma unroll 4
      for (int k = 0; k < Kc; ++k) {
        float y = bias;
#pragma unroll
        for (int c = 0; c < 6; ++c) y = fmaf(x0s[w][c][k], W[c], y);
        sum += y;
        sq = fmaf(y, y, sq);
      }
    }
    part0[(size_t)wid * 128 + lane] = sum;
    part0[(size_t)wid * 128 + 64 + lane] = sq;
  }
}

// One block per channel; 256-thread fixed-order tree (deterministic, double).
__global__ __launch_bounds__(256)
void reduce_k(const float* __restrict__ part, int nblk, int nch,
              const float* __restrict__ g, const float* __restrict__ be,
              float* __restrict__ AB) {
  const int o = blockIdx.x;
  const int t = threadIdx.x;
  double sum = 0.0, sq = 0.0;
  for (int i = t; i < nblk; i += 256) {
    sum += (double)part[(size_t)i * (2 * nch) + o];
    sq  += (double)part[(size_t)i * (2 * nch) + nch + o];
  }
  __shared__ double ls[256], lq[256];
  ls[t] = sum; lq[t] = sq;
  __syncthreads();
  for (int s = 128; s > 0; s >>= 1) {
    if (t < s) { ls[t] += ls[t + s]; lq[t] += lq[t + s]; }
    __syncthreads();
  }
  if (t == 0) {
    double m = ls[0] / (double)Pc;
    double v = lq[0] / (double)Pc - m * m;
    double A = (double)g[o] / sqrt(v + 1e-5);
    AB[o] = (float)A;
    AB[nch + o] = (float)((double)be[o] - m * A);
  }
}

// reduce layer-2 stats fused with the final affine+relu epilogue.
__global__ __launch_bounds__(256)
void reduce2_final_k(const float* __restrict__ part, int nblk,
                     const float* __restrict__ g, const float* __restrict__ be,
                     const float* __restrict__ maxy2,
                     float* __restrict__ out) {
  const int o = blockIdx.x;          // 0..127
  const int t = threadIdx.x;
  double sum = 0.0, sq = 0.0;
  for (int i = t; i < nblk; i += 256) {
    sum += (double)part[(size_t)i * 256 + o];
    sq  += (double)part[(size_t)i * 256 + 128 + o];
  }
  __shared__ double ls[256], lq[256];
  ls[t] = sum; lq[t] = sq;
  __syncthreads();
  for (int s = 128; s > 0; s >>= 1) {
    if (t < s) { ls[t] += ls[t + s]; lq[t] += lq[t + s]; }
    __syncthreads();
  }
  __shared__ float sA, sB;
  if (t == 0) {
    double m = ls[0] / (double)Pc;
    double v = lq[0] / (double)Pc - m * m;
    double A = (double)g[o] / sqrt(v + 1e-5);
    sA = (float)A;
    sB = (float)((double)be[o] - m * A);
  }
  __syncthreads();
  const float A = sA, B = sB;
  for (int grp = t; grp < Bc * Sc; grp += 256) {
    float v = maxy2[(size_t)grp * 128 + o];
    out[(size_t)grp * 128 + o] = fmaxf(fmaf(v, A, B), 0.f);
  }
}

// ---------------------------------------------------------------------------
// pass_b (r21): minimal r9 form + MANUAL 2-WAY o-INTERLEAVE. r10 measurement:
// pass_c = 143us -> ~670 cyc per o-iteration per SIMD. Mechanism: the per-o
// wave-uniform weight-row fetch compiles to s_load batches, waitable only by
// a full lgkmcnt(0) drain at scalar-L2-miss latency (w1/w2 stream through the
// 16KB K$ every block); all lockstep waves stall together, TLP hides nothing.
// Interleaving o and o+1 lets the compiler issue BOTH rows' s_loads in one
// batch with one drain: stall/o halves, FMA block per drain doubles.
// Per-o math, FP order, and store addresses untouched -> y1 bit-identical.
// ---------------------------------------------------------------------------
__global__ __launch_bounds__(256, 1)
void pass_b(const float* __restrict__ x0, const float* __restrict__ w0,
            const float* __restrict__ b0, const float* __restrict__ AB0,
            const float* __restrict__ w1, const float* __restrict__ b1,
            float* __restrict__ y1) {
  const int p = blockIdx.x * 256 + threadIdx.x;

  float xin[6];
#pragma unroll
  for (int c = 0; c < 6; ++c) xin[c] = x0[(size_t)c * Pc + p];

  v2f x1p[32];
#pragma unroll
  for (int j = 0; j < 32; ++j) {
    float y0v = b0[2 * j];
#pragma unroll
    for (int c = 0; c < 6; ++c) y0v = fmaf(xin[c], w0[(2 * j) * 6 + c], y0v);
    x1p[j].x = fmaxf(fmaf(y0v, AB0[2 * j], AB0[64 + 2 * j]), 0.f);
    float y1v = b0[2 * j + 1];
#pragma unroll
    for (int c = 0; c < 6; ++c) y1v = fmaf(xin[c], w0[(2 * j + 1) * 6 + c], y1v);
    x1p[j].y = fmaxf(fmaf(y1v, AB0[2 * j + 1], AB0[64 + 2 * j + 1]), 0.f);
  }

  const v2f* __restrict__ w1v = (const v2f*)w1;

  for (int o = 0; o < 64; o += 2) {
    // two independent output channels; both weight rows fetched in one batch
    v2f a01; a01.x = b1[o];     a01.y = 0.f;
    v2f a23; a23.x = 0.f;       a23.y = 0.f;
    v2f c01; c01.x = b1[o + 1]; c01.y = 0.f;
    v2f c23; c23.x = 0.f;       c23.y = 0.f;
#pragma unroll
    for (int c2 = 0; c2 < 32; c2 += 2) {
      a01 = PKFMA(x1p[c2 + 0], w1v[o * 32 + c2 + 0], a01);
      a23 = PKFMA(x1p[c2 + 1], w1v[o * 32 + c2 + 1], a23);
      c01 = PKFMA(x1p[c2 + 0], w1v[(o + 1) * 32 + c2 + 0], c01);
      c23 = PKFMA(x1p[c2 + 1], w1v[(o + 1) * 32 + c2 + 1], c23);
    }
    y1[(size_t)o * Pc + p]       = (a01.x + a01.y) + (a23.x + a23.y);
    y1[(size_t)(o + 1) * Pc + p] = (c01.x + c01.y) + (c23.x + c23.y);
  }
}

// stats1_k: per-channel sum/sumsq partials from the y1 planes (r9 form).
__global__ __launch_bounds__(256)
void stats1_k(const float* __restrict__ y1, float* __restrict__ pair1) {
  const int b = blockIdx.x;
  const int o = b >> 4, seg = b & 15;
  const int t = threadIdx.x;
  const float* plane = y1 + (size_t)o * Pc + (size_t)seg * 16384;
  float sum = 0.f, sq = 0.f;
  for (int i = t; i < 16384; i += 256) {
    float v = plane[i];
    sum += v;
    sq = fmaf(v, v, sq);
  }
  __shared__ float ls[256], lq[256];
  ls[t] = sum; lq[t] = sq;
  __syncthreads();
  for (int s = 128; s > 0; s >>= 1) {
    if (t < s) { ls[t] += ls[t + s]; lq[t] += lq[t + s]; }
    __syncthreads();
  }
  if (t == 0) {
    pair1[(size_t)b * 2 + 0] = ls[0];
    pair1[(size_t)b * 2 + 1] = lq[0];
  }
}

// Tiny deterministic double reduce over the 16 segment pairs per channel.
__global__ __launch_bounds__(64)
void reduceAB_pairs_k(const float* __restrict__ pair, int nseg,
                      const float* __restrict__ g, const float* __restrict__ be,
                      float* __restrict__ AB, int nch) {
  const int o = blockIdx.x;
  if (threadIdx.x == 0) {
    double sum = 0.0, sq = 0.0;
    for (int s = 0; s < nseg; ++s) {
      sum += (double)pair[(size_t)(o * nseg + s) * 2 + 0];
      sq  += (double)pair[(size_t)(o * nseg + s) * 2 + 1];
    }
    double m = sum / (double)Pc;
    double v = sq / (double)Pc - m * m;
    double A = (double)g[o] / sqrt(v + 1e-5);
    AB[o] = (float)A;
    AB[nch + o] = (float)((double)be[o] - m * A);
  }
}

// pass_c (r21): MANUAL 2-WAY o-INTERLEAVE (same batched-drain rationale).
// Per-o conv math, maxy2/stats epilogues, FP order all unchanged per o.
__global__ __launch_bounds__(256, 1)
void pass_c(const float* __restrict__ y1, const float* __restrict__ AB1,
            const float* __restrict__ w2, const float* __restrict__ b2,
            float* __restrict__ maxy2, float* __restrict__ part2) {
  const int p = blockIdx.x * 256 + threadIdx.x;
  const int lane = threadIdx.x & 63, w = threadIdx.x >> 6;
  const int grp = p >> 5;

  v2f x2p[32];
#pragma unroll
  for (int c = 0; c < 64; c += 2) {
    float v0 = y1[(size_t)c * Pc + p];
    float v1 = y1[(size_t)(c + 1) * Pc + p];
    x2p[c >> 1].x = fmaxf(fmaf(v0, AB1[c], AB1[64 + c]), 0.f);
    x2p[c >> 1].y = fmaxf(fmaf(v1, AB1[c + 1], AB1[64 + c + 1]), 0.f);
  }

  const v2f* __restrict__ w2v = (const v2f*)w2;

  __shared__ float ssum[4][128][9], ssq[4][128][9];  // padded: stride 9

  for (int o = 0; o < 128; o += 2) {
    v2f a01; a01.x = b2[o];     a01.y = 0.f;
    v2f a23; a23.x = 0.f;       a23.y = 0.f;
    v2f c01; c01.x = b2[o + 1]; c01.y = 0.f;
    v2f c23; c23.x = 0.f;       c23.y = 0.f;
#pragma unroll
    for (int c2 = 0; c2 < 32; c2 += 2) {
      a01 = PKFMA(x2p[c2 + 0], w2v[o * 32 + c2 + 0], a01);
      a23 = PKFMA(x2p[c2 + 1], w2v[o * 32 + c2 + 1], a23);
      c01 = PKFMA(x2p[c2 + 0], w2v[(o + 1) * 32 + c2 + 0], c01);
      c23 = PKFMA(x2p[c2 + 1], w2v[(o + 1) * 32 + c2 + 1], c23);
    }
    float acc0 = (a01.x + a01.y) + (a23.x + a23.y);
    float acc1 = (c01.x + c01.y) + (c23.x + c23.y);

    // epilogue for channel o (unchanged per-o logic)
    {
      float mx = acc0;
#pragma unroll
      for (int off = 16; off > 0; off >>= 1) mx = fmaxf(mx, __shfl_xor(mx, off));
      if ((lane & 31) == 0) maxy2[(size_t)grp * 128 + o] = mx;

      float sv = acc0 + __shfl_xor(acc0, 1);
      sv += __shfl_xor(sv, 2);
      sv += __shfl_xor(sv, 4);
      float q = acc0 * acc0;
      float qv = q + __shfl_xor(q, 1);
      qv += __shfl_xor(qv, 2);
      qv += __shfl_xor(qv, 4);
      if ((lane & 7) == 0) {
        ssum[w][o][lane >> 3] = sv;
        ssq[w][o][lane >> 3] = qv;
      }
    }
    // epilogue for channel o+1
    {
      float mx = acc1;
#pragma unroll
      for (int off = 16; off > 0; off >>= 1) mx = fmaxf(mx, __shfl_xor(mx, off));
      if ((lane & 31) == 0) maxy2[(size_t)grp * 128 + o + 1] = mx;

      float sv = acc1 + __shfl_xor(acc1, 1);
      sv += __shfl_xor(sv, 2);
      sv += __shfl_xor(sv, 4);
      float q = acc1 * acc1;
      float qv = q + __shfl_xor(q, 1);
      qv += __shfl_xor(qv, 2);
      qv += __shfl_xor(qv, 4);
      if ((lane & 7) == 0) {
        ssum[w][o + 1][lane >> 3] = sv;
        ssq[w][o + 1][lane >> 3] = qv;
      }
    }
  }
  __syncthreads();
  {
    const int o = threadIdx.x & 127;
    const bool isq = threadIdx.x >= 128;
    float s = 0.f;
#pragma unroll
    for (int ww = 0; ww < 4; ++ww)
      for (int k = 0; k < 8; ++k)
        s += isq ? ssq[ww][o][k] : ssum[ww][o][k];
    part2[blockIdx.x * 256 + threadIdx.x] = s;
  }
}

extern "C" void kernel_launch(void* const* d_in, const int* in_sizes, int n_in,
                              void* d_out, int out_size, void* d_ws, size_t ws_size,
                              hipStream_t stream) {
  const float* data = (const float*)d_in[0];
  const float* feat = (const float*)d_in[1];
  const float* w0 = (const float*)d_in[2];
  const float* b0 = (const float*)d_in[3];
  const float* g0 = (const float*)d_in[4];
  const float* be0 = (const float*)d_in[5];
  const float* w1 = (const float*)d_in[6];
  const float* b1 = (const float*)d_in[7];
  const float* g1 = (const float*)d_in[8];
  const float* be1 = (const float*)d_in[9];
  const float* w2 = (const float*)d_in[10];
  const float* b2 = (const float*)d_in[11];
  const float* g2 = (const float*)d_in[12];
  const float* be2 = (const float*)d_in[13];
  float* out = (float*)d_out;

  float* ws = (float*)d_ws;
  int* idx_pub = (int*)ws; ws += (size_t)Bc * Sc;      // 8192 ints
  float* x0 = ws;      ws += (size_t)6 * Pc;
  float* y1 = ws;      ws += (size_t)64 * Pc;          // [ch][point] planes
  float* maxy2 = ws;   ws += (size_t)Bc * Sc * 128;
  float* part0 = ws;   ws += (size_t)NBALL_WAVES * 128;
  float* pair1 = ws;   ws += 1024 * 2;
  float* part2 = ws;   ws += 1024 * 256;
  float* AB0 = ws;     ws += 128;
  float* AB1 = ws;     ws += 128;

  // re-poison the publication slots every graph replay
  hipMemsetAsync(idx_pub, 0xFF, (size_t)Bc * Sc * sizeof(int), stream);

  fps_ball_fused<<<Bc + NBALL_BLK, 256, 0, stream>>>(data, feat, w0, b0,
                                                     idx_pub, out, x0, part0);
  reduce_k<<<64, 256, 0, stream>>>(part0, NBALL_WAVES, 64, g0, be0, AB0);
  pass_b<<<Pc / 256, 256, 0, stream>>>(x0, w0, b0, AB0, w1, b1, y1);
  stats1_k<<<1024, 256, 0, stream>>>(y1, pair1);
  reduceAB_pairs_k<<<64, 64, 0, stream>>>(pair1, 16, g1, be1, AB1, 64);
  pass_c<<<Pc / 256, 256, 0, stream>>>(y1, AB1, w2, b2, maxy2, part2);
  reduce2_final_k<<<128, 256, 0, stream>>>(part2, 1024, g2, be2, maxy2,
                                           out + (size_t)Bc * Sc * 3);
}